// Round 12
// baseline (1608.680 us; speedup 1.0000x reference)
//
#include <hip/hip_runtime.h>

typedef unsigned int u32;
typedef int i32x4 __attribute__((ext_vector_type(4)));

#define DIN 2048              // K elements; int8 row = 2048 bytes
#define DOUT 8192
#define MROWS 8192            // B*S
#define NELEM_W (8192 * 2048)

// workspace layout (bytes)
#define WS_PART 0                        // double[2048]
#define WS_WFAC 16384                    // float
#define WS_ROWFAC 16640                  // float[8192]
#define WS_XQ 49408                      // int8[8192*2048]
#define WS_WQ (49408 + 16777216)         // int8[8192*2048]

// ---------------- fused stage 1: weight abs-partials + act RMS/quant --------
// blocks 0..2047: |w| partial sums (w read overlaps x read below)
// blocks 2048..10239: per-row RMS-norm + int8 quant of x (independent of wfac)
__global__ void k_pre1(const float* __restrict__ w, double* __restrict__ part,
                       const float* __restrict__ x, u32* __restrict__ xq,
                       float* __restrict__ rowfac) {
    const int t = threadIdx.x;
    if (blockIdx.x < 2048) {
        const float4* w4 = (const float4*)w;
        const unsigned b = blockIdx.x;
        float s = 0.f;
        for (unsigned i = b * 256u + t; i < (NELEM_W / 4); i += 2048u * 256u) {
            float4 v = w4[i];
            s += fabsf(v.x) + fabsf(v.y) + fabsf(v.z) + fabsf(v.w);
        }
        double d = (double)s;
        #pragma unroll
        for (int o = 32; o; o >>= 1) d += __shfl_down(d, o);
        __shared__ double redd[4];
        if ((t & 63) == 0) redd[t >> 6] = d;
        __syncthreads();
        if (t == 0) part[b] = redd[0] + redd[1] + redd[2] + redd[3];
        return;
    }
    const int row = blockIdx.x - 2048;
    const float4* xr = (const float4*)(x + (size_t)row * DIN);
    float4 v0 = xr[t], v1 = xr[t + 256];
    float ss = v0.x * v0.x + v0.y * v0.y + v0.z * v0.z + v0.w * v0.w
             + v1.x * v1.x + v1.y * v1.y + v1.z * v1.z + v1.w * v1.w;
    __shared__ float red[4];
    #pragma unroll
    for (int o = 32; o; o >>= 1) ss += __shfl_down(ss, o);
    if ((t & 63) == 0) red[t >> 6] = ss;
    __syncthreads();
    ss = red[0] + red[1] + red[2] + red[3];
    const float r = 1.0f / sqrtf(ss * (1.0f / DIN) + 1.1920929e-7f);
    float xn[8] = {v0.x * r, v0.y * r, v0.z * r, v0.w * r,
                   v1.x * r, v1.y * r, v1.z * r, v1.w * r};
    float am = 0.f;
    #pragma unroll
    for (int j = 0; j < 8; ++j) am = fmaxf(am, fabsf(xn[j]));
    __syncthreads();
    #pragma unroll
    for (int o = 32; o; o >>= 1) am = fmaxf(am, __shfl_down(am, o));
    if ((t & 63) == 0) red[t >> 6] = am;
    __syncthreads();
    am = fmaxf(fmaxf(red[0], red[1]), fmaxf(red[2], red[3]));
    const float amc = fmaxf(am, 1e-5f);
    const float s = 127.0f / amc;
    int q[8];
    #pragma unroll
    for (int j = 0; j < 8; ++j)
        q[j] = (int)fminf(fmaxf(rintf(xn[j] * s), -128.f), 127.f);
    u32* xo = xq + (size_t)row * (DIN / 4);
    xo[t] = (u32)(q[0] & 255) | ((u32)(q[1] & 255) << 8) |
            ((u32)(q[2] & 255) << 16) | ((u32)(q[3] & 255) << 24);
    xo[t + 256] = (u32)(q[4] & 255) | ((u32)(q[5] & 255) << 8) |
                  ((u32)(q[6] & 255) << 16) | ((u32)(q[7] & 255) << 24);
    if (t == 0) rowfac[row] = amc * (1.0f / 127.0f);
}

// ---------------- weight abs-mean (stage 2) ---------------------------------
__global__ void k_wfin(const double* __restrict__ part, float* __restrict__ wfac) {
    const int t = threadIdx.x;
    double s = 0.0;
    #pragma unroll
    for (int j = 0; j < 8; ++j) s += part[t + j * 256];
    #pragma unroll
    for (int o = 32; o; o >>= 1) s += __shfl_down(s, o);
    __shared__ double red[4];
    if ((t & 63) == 0) red[t >> 6] = s;
    __syncthreads();
    if (t == 0) {
        double mean = (red[0] + red[1] + red[2] + red[3]) * (1.0 / (double)NELEM_W);
        *wfac = fmaxf((float)mean, 1e-5f);
    }
}

// ---------------- ternary weight quant: w -> int8 {-1,0,1} ------------------
__global__ void k_wquant(const float* __restrict__ w, const float* __restrict__ wfac,
                         u32* __restrict__ wq) {
    const float scale = 1.0f / *wfac;
    const float4* w4 = (const float4*)w;
    for (unsigned i = blockIdx.x * 256u + threadIdx.x; i < (NELEM_W / 4); i += 2048u * 256u) {
        float4 v = w4[i];
        int q0 = (int)fminf(fmaxf(rintf(v.x * scale), -1.f), 1.f);
        int q1 = (int)fminf(fmaxf(rintf(v.y * scale), -1.f), 1.f);
        int q2 = (int)fminf(fmaxf(rintf(v.z * scale), -1.f), 1.f);
        int q3 = (int)fminf(fmaxf(rintf(v.w * scale), -1.f), 1.f);
        wq[i] = (u32)(q0 & 255) | ((u32)(q1 & 255) << 8) |
                ((u32)(q2 & 255) << 16) | ((u32)(q3 & 255) << 24);
    }
}

// ---------------- 256x128 int8 GEMM, 3 blocks/CU (24 waves/CU) ---------------
// r11 body verbatim (passed, 165us, 0 conflicts, VGPR 60); LDS 48KB -> 3
// resident blocks with __launch_bounds__(512, 6). Independent blocks desync;
// testing whether concurrency 2->3 moves the invariant ~165us plateau.
__launch_bounds__(512, 6)
__global__ void k_gemm(const char* __restrict__ A, const char* __restrict__ Bw,
                       const float* __restrict__ rowfac, const float* __restrict__ wfac,
                       float* __restrict__ out) {
    __shared__ __attribute__((aligned(16))) char smb[49152];

    const int t = threadIdx.x;
    const int l = t & 63, w = t >> 6;
    const int wm = w >> 1, wn = w & 1;
    const int lr = l & 15, lc = l >> 4;
    // verified zero-conflict read offset within a [rows][64B] buffer
    const int laneF = lr * 64 + ((lc ^ ((lr >> 1) & 3)) * 16);
    // staging: thread t writes LDS linear t*16 (row t>>2, phys granule t&3);
    // source logical granule = (t&3) ^ ((t>>3)&3)
    const int srow = t >> 2;
    const int sgl = ((t & 3) ^ ((t >> 3) & 3)) * 16;

    // XCD-partitioned mapping: per XCD, 4 contiguous bm; bn sweeps 0..63.
    const int bid = blockIdx.x;
    const int g = (bid & 7) * 256 + (bid >> 3);
    const int bm = g >> 6, bn = g & 63;
    const char* Ab = A + (size_t)(bm * 256) * DIN;
    const char* Bb = Bw + (size_t)(bn * 128) * DIN;

    i32x4 acc[4][4] = {};          // [m][n], 64 regs
    i32x4 fb[4], fa01[2], fa23[2]; // 32 regs

#define STG(tB, s) do {                                                           \
    _Pragma("unroll")                                                             \
    for (int j_ = 0; j_ < 2; ++j_)                                                \
        __builtin_amdgcn_global_load_lds(                                         \
            (const __attribute__((address_space(1))) void*)(Ab + (size_t)(j_ * 128 + srow) * DIN + (tB) + sgl), \
            (__attribute__((address_space(3))) void*)(smb + (s) * 16384 + j_ * 8192 + t * 16), 16, 0, 0); \
    __builtin_amdgcn_global_load_lds(                                             \
        (const __attribute__((address_space(1))) void*)(Bb + (size_t)srow * DIN + (tB) + sgl), \
        (__attribute__((address_space(3))) void*)(smb + 32768 + (s) * 8192 + t * 16), 16, 0, 0); \
} while (0)

#define RDA(s, m_) (*(const i32x4*)(smb + (s) * 16384 + (wm * 64 + (m_) * 16) * 64 + laneF))
#define RDB(s, n_) (*(const i32x4*)(smb + 32768 + (s) * 8192 + (wn * 64 + (n_) * 16) * 64 + laneF))

#define MFMA_G(mB, fA) do {                                                       \
    __builtin_amdgcn_s_setprio(1);                                                \
    _Pragma("unroll")                                                             \
    for (int i_ = 0; i_ < 2; ++i_)                                                \
        _Pragma("unroll")                                                         \
        for (int n_ = 0; n_ < 4; ++n_)                                            \
            acc[(mB) + i_][n_] = __builtin_amdgcn_mfma_i32_16x16x64_i8(           \
                fA[i_], fb[n_], acc[(mB) + i_][n_], 0, 0, 0);                     \
    __builtin_amdgcn_s_setprio(0);                                                \
} while (0)

#define LGKM0 asm volatile("s_waitcnt lgkmcnt(0)" ::: "memory")
#define VM(n) asm volatile("s_waitcnt vmcnt(" #n ")" ::: "memory")
#define BAR __builtin_amdgcn_s_barrier()

#define TILE(s, o, STG_STMT, GATE_STMT) do {                                      \
    LGKM0;                      /* T's 8 frag reads complete */                   \
    BAR;                        /* slot s free to overwrite */                    \
    STG_STMT;                   /* T+2 -> s */                                    \
    GATE_STMT;                  /* T+1 resident (counted) */                      \
    BAR;                                                                          \
    MFMA_G(0, fa01);            /* T m0-1 (old fb) */                             \
    fa01[0] = RDA(o, 0);                                                          \
    fa01[1] = RDA(o, 1);                                                          \
    MFMA_G(2, fa23);            /* T m2-3 (old fb — last use) */                  \
    fa23[0] = RDA(o, 2);                                                          \
    fa23[1] = RDA(o, 3);                                                          \
    fb[0] = RDB(o, 0); fb[1] = RDB(o, 1);                                         \
    fb[2] = RDB(o, 2); fb[3] = RDB(o, 3);  /* drain under next VM gate */         \
} while (0)

    // prologue
    STG(0, 0);
    STG(64, 1);
    VM(3);
    BAR;
    fb[0] = RDB(0, 0); fb[1] = RDB(0, 1); fb[2] = RDB(0, 2); fb[3] = RDB(0, 3);
    fa01[0] = RDA(0, 0); fa01[1] = RDA(0, 1);
    fa23[0] = RDA(0, 2); fa23[1] = RDA(0, 3);

    #pragma unroll 1
    for (int p = 0; p < 15; ++p) {        // tiles T0..T29
        const int tB = p * 128;
        TILE(0, 1, STG(tB + 128, 0), VM(3));
        TILE(1, 0, STG(tB + 192, 1), VM(3));
    }
    TILE(0, 1, (void)0, VM(0));           // T30; gate T31
    LGKM0;                                // T31 straight-line
    MFMA_G(0, fa01);
    MFMA_G(2, fa23);

    // epilogue
    const float wf = *wfac;
    const int c0 = bn * 128 + wn * 64 + lr;
    #pragma unroll
    for (int m = 0; m < 4; ++m) {
        #pragma unroll
        for (int r = 0; r < 4; ++r) {
            const int grow = bm * 256 + wm * 64 + m * 16 + lc * 4 + r;
            const float s = rowfac[grow] * wf;
            const size_t ob = (size_t)grow * DOUT + c0;
            #pragma unroll
            for (int n = 0; n < 4; ++n)
                out[ob + n * 16] = (float)acc[m][n][r] * s;
        }
    }
#undef STG
#undef RDA
#undef RDB
#undef MFMA_G
#undef LGKM0
#undef VM
#undef BAR
#undef TILE
}

extern "C" void kernel_launch(void* const* d_in, const int* in_sizes, int n_in,
                              void* d_out, int out_size, void* d_ws, size_t ws_size,
                              hipStream_t stream) {
    const float* x = (const float*)d_in[0];   // [4,2048,2048]
    const float* wt = (const float*)d_in[1];  // [8192,2048]
    float* out = (float*)d_out;               // [4,2048,8192] fp32
    char* ws = (char*)d_ws;

    double* part = (double*)(ws + WS_PART);
    float* wfac = (float*)(ws + WS_WFAC);
    float* rowfac = (float*)(ws + WS_ROWFAC);
    u32* xq = (u32*)(ws + WS_XQ);
    u32* wq = (u32*)(ws + WS_WQ);

    k_pre1<<<2048 + MROWS, 256, 0, stream>>>(wt, part, x, xq, rowfac);
    k_wfin<<<1, 256, 0, stream>>>(part, wfac);
    k_wquant<<<2048, 256, 0, stream>>>(wt, wfac, wq);
    k_gemm<<<2048, 512, 0, stream>>>((const char*)xq, (const char*)wq, rowfac, wfac, out);
}